// Round 4
// baseline (162.402 us; speedup 1.0000x reference)
//
#include <hip/hip_runtime.h>
#include <hip/hip_bf16.h>
#include <stdint.h>

// out[b,t,o] = bias[o] + sum_{c<7,m<8,h<3} W[o, c*8+m, h] * Z[b, c*8+m, (t+h-1)&2047]
// Z[b, cm, s] = (s >= 168) ? x[b, s-24m, c] : 0
//
// Tap decomposition: out = sum_h G_shift(h-1) @ Wh[h]^T with
//   G[b*2048+t][c*8+m] = (t>=168) ? x[b, t-24m, c] : 0,  K=56 padded to 72 bf16
// (144 B row; stride 144 B => 2-way LDS bank alias only, free).
// Time wrap (&2047) matches the reference's circular pad.

#define TAO    24
#define MTAPS  7
#define C_IN   7
#define SEQ    2048
#define DMODEL 512
#define KP     72      // padded K per tap (bf16), 144 B
#define RB     144     // row bytes
#define NROWS  65536   // 32*2048
#define BM     128
#define BN     64
#define AROWS  130     // BM + 2 halo rows
#define A_CHUNKS (AROWS * 9)          // 1170
#define B_CHUNKS (3 * BN * 9)         // 1728
#define BS_H_STRIDE (BN * RB)         // 9216 B per tap in LDS

typedef __attribute__((ext_vector_type(8))) short frag_ab;  // 8 bf16
typedef __attribute__((ext_vector_type(4))) float frag_cd;  // 4 fp32

// ---------------- phase 1: build G (65536 x 72 bf16) + Wh (3 x 512 x 72 bf16)
// blocks [0,256): G rows;  blocks [256,262): Wb2[h][o][cm] = W[o*168+cm*3+h]
__global__ __launch_bounds__(256)
void prep_kernel(const float* __restrict__ x, const float* __restrict__ W,
                 __hip_bfloat16* __restrict__ G, __hip_bfloat16* __restrict__ Wb2)
{
    const int tid = threadIdx.x;
    if (blockIdx.x < 256) {
        const int row = blockIdx.x * 256 + tid;
        const int b   = row >> 11;
        const int t   = row & (SEQ - 1);
        const float* xb = x + b * (SEQ * C_IN);

        union { __hip_bfloat16 h[KP]; int4 v[9]; } u;
#pragma unroll
        for (int j = 0; j < 9; j++) u.v[j] = (int4){0, 0, 0, 0};

        if (t >= MTAPS * TAO) {
#pragma unroll
            for (int m = 0; m < 8; m++) {
                const float* p = xb + (t - TAO * m) * C_IN;
#pragma unroll
                for (int c = 0; c < C_IN; c++)
                    u.h[c * 8 + m] = __float2bfloat16(p[c]);
            }
        }
        int4* dst = (int4*)((char*)G + (size_t)row * RB);
#pragma unroll
        for (int j = 0; j < 9; j++) dst[j] = u.v[j];
    } else {
        const int idx = (blockIdx.x - 256) * 256 + tid;   // 1536 tasks
        const int h = idx / DMODEL;
        const int o = idx - h * DMODEL;

        union { __hip_bfloat16 s[KP]; int4 v[9]; } u;
#pragma unroll
        for (int j = 0; j < 9; j++) u.v[j] = (int4){0, 0, 0, 0};
#pragma unroll
        for (int cm = 0; cm < 56; cm++)
            u.s[cm] = __float2bfloat16(W[o * 168 + cm * 3 + h]);

        int4* dst = (int4*)((char*)Wb2 + (size_t)idx * RB);
#pragma unroll
        for (int j = 0; j < 9; j++) dst[j] = u.v[j];
    }
}

// ---------------- phase 2: GEMM ----------------
__global__ __launch_bounds__(256, 3)
void gemm_kernel(const __hip_bfloat16* __restrict__ G,
                 const __hip_bfloat16* __restrict__ Wb2,
                 const float* __restrict__ bias,
                 float* __restrict__ out)
{
    __shared__ __align__(16) char lds[AROWS * RB + 3 * BN * RB];  // 18720 + 27648 = 46368 B
    char* As = lds;
    char* Bs = lds + AROWS * RB;

    const int tid = threadIdx.x;
    const int nb  = blockIdx.x & 7;      // 8 N-blocks
    const int mb  = blockIdx.x >> 3;     // 512 M-blocks
    const int b   = mb >> 4;
    const int t0  = (mb & 15) * BM;
    const int o0  = nb * BN;

    // --- stage A: 130 rows of G (halo +/-1), circular wrap (matches reference)
    {
        const char* Gb = (const char*)G + (size_t)b * SEQ * RB;
        for (int q = tid; q < A_CHUNKS; q += 256) {
            const int row = q / 9;
            const int c16 = q - row * 9;
            const int srow = (t0 - 1 + row + SEQ) & (SEQ - 1);
            __builtin_amdgcn_global_load_lds(
                (const __attribute__((address_space(1))) uint32_t*)(Gb + (size_t)srow * RB + c16 * 16),
                (__attribute__((address_space(3))) uint32_t*)(As + q * 16), 16, 0, 0);
        }
    }
    // --- stage B: 3 taps x 64 rows of Wb2
    {
        for (int q = tid; q < B_CHUNKS; q += 256) {
            const int h = q / (BN * 9);
            const int rem = q - h * (BN * 9);
            const char* src = (const char*)Wb2 + ((size_t)(h * DMODEL + o0)) * RB + rem * 16;
            __builtin_amdgcn_global_load_lds(
                (const __attribute__((address_space(1))) uint32_t*)src,
                (__attribute__((address_space(3))) uint32_t*)(Bs + q * 16), 16, 0, 0);
        }
    }

    // --- wave geometry + bias preload (overlaps staging latency)
    const int wave = tid >> 6;
    const int lane = tid & 63;
    const int wm   = (wave >> 1) * 64;
    const int wn   = (wave & 1) * 32;
    const int l15  = lane & 15;
    const int quad = lane >> 4;

    float bv[2];
#pragma unroll
    for (int ni = 0; ni < 2; ni++)
        bv[ni] = bias[o0 + wn + ni * 16 + l15];

    __syncthreads();

    // --- MFMA: 4 waves as 2(M) x 2(N); wave tile 64x32 = 4x2 of 16x16
    frag_cd acc[4][2];
#pragma unroll
    for (int i = 0; i < 4; i++)
#pragma unroll
        for (int j = 0; j < 2; j++)
            acc[i][j] = (frag_cd){0.f, 0.f, 0.f, 0.f};

#pragma unroll
    for (int h = 0; h < 3; h++) {
#pragma unroll
        for (int kc = 0; kc < 2; kc++) {
            const int kbyte = kc * 64 + quad * 16;
            frag_ab a[4], bf[2];
#pragma unroll
            for (int mi = 0; mi < 4; mi++)
                a[mi] = *(const frag_ab*)(As + (wm + mi * 16 + l15 + h) * RB + kbyte);
#pragma unroll
            for (int ni = 0; ni < 2; ni++)
                bf[ni] = *(const frag_ab*)(Bs + h * BS_H_STRIDE + (wn + ni * 16 + l15) * RB + kbyte);
#pragma unroll
            for (int mi = 0; mi < 4; mi++)
#pragma unroll
                for (int ni = 0; ni < 2; ni++)
                    acc[mi][ni] = __builtin_amdgcn_mfma_f32_16x16x32_bf16(
                        a[mi], bf[ni], acc[mi][ni], 0, 0, 0);
        }
    }

    // --- epilogue: C/D layout col = lane&15 (n=o), row = quad*4 + reg (m=t)
    const size_t row0 = (size_t)mb * BM;
#pragma unroll
    for (int ni = 0; ni < 2; ni++) {
        const int o = o0 + wn + ni * 16 + l15;
#pragma unroll
        for (int mi = 0; mi < 4; mi++) {
            const size_t rbase = row0 + wm + mi * 16 + quad * 4;
#pragma unroll
            for (int reg = 0; reg < 4; reg++) {
                out[(rbase + reg) * DMODEL + o] = acc[mi][ni][reg] + bv[ni];
            }
        }
    }
}

// ---------------- fallback (round-1, known-correct, no ws) ----------------
#define KDIM  168
#define KPAD  192
#define FLDK  200
__global__ __launch_bounds__(256, 1)
void fused_tokenconv_kernel(const float* __restrict__ x,
                            const float* __restrict__ W,
                            const float* __restrict__ bias,
                            float* __restrict__ out)
{
    __shared__ __hip_bfloat16 As[128][FLDK];
    __shared__ __hip_bfloat16 Bs[128][FLDK];
    const int tid = threadIdx.x;
    const int blk = blockIdx.x;
    const int nb  = blk & 3;
    const int mb  = blk >> 2;
    const int b   = mb >> 4;
    const int t0  = (mb & 15) * 128;
    const int o0  = nb * 128;
    const float* xb = x + b * (SEQ * C_IN);

    for (int idx = tid; idx < 128 * KPAD; idx += 256) {
        int o_l = idx / KPAD;
        int i   = idx - o_l * KPAD;
        float v = (i < KDIM) ? W[(o0 + o_l) * KDIM + i] : 0.0f;
        Bs[o_l][i] = __float2bfloat16(v);
    }
    for (int idx = tid; idx < 128 * KPAD; idx += 256) {
        int t_l = idx / KPAD;
        int i   = idx - t_l * KPAD;
        float v = 0.0f;
        if (i < KDIM) {
            int c = i / 24;
            int r = i - c * 24;
            int m = r / 3;
            int h = r - m * 3;
            int s = (t0 + t_l + h - 1 + SEQ) & (SEQ - 1);
            if (s >= MTAPS * TAO) v = xb[(s - TAO * m) * C_IN + c];
        }
        As[t_l][i] = __float2bfloat16(v);
    }
    __syncthreads();

    const int wave = tid >> 6;
    const int lane = tid & 63;
    const int wm   = (wave >> 1) * 64;
    const int wn   = (wave & 1) * 64;
    const int l15  = lane & 15;
    const int quad = lane >> 4;

    frag_cd acc[4][4];
#pragma unroll
    for (int i = 0; i < 4; i++)
#pragma unroll
        for (int j = 0; j < 4; j++)
            acc[i][j] = (frag_cd){0.f, 0.f, 0.f, 0.f};

#pragma unroll
    for (int kc = 0; kc < KPAD / 32; kc++) {
        const int kof = kc * 32 + quad * 8;
        frag_ab a[4], bf[4];
#pragma unroll
        for (int mi = 0; mi < 4; mi++)
            a[mi] = *(const frag_ab*)&As[wm + mi * 16 + l15][kof];
#pragma unroll
        for (int ni = 0; ni < 4; ni++)
            bf[ni] = *(const frag_ab*)&Bs[wn + ni * 16 + l15][kof];
#pragma unroll
        for (int mi = 0; mi < 4; mi++)
#pragma unroll
            for (int ni = 0; ni < 4; ni++)
                acc[mi][ni] = __builtin_amdgcn_mfma_f32_16x16x32_bf16(
                    a[mi], bf[ni], acc[mi][ni], 0, 0, 0);
    }
    float* outb = out + (size_t)b * SEQ * DMODEL;
#pragma unroll
    for (int ni = 0; ni < 4; ni++) {
        const int o  = o0 + wn + ni * 16 + l15;
        const float bvv = bias[o];
#pragma unroll
        for (int mi = 0; mi < 4; mi++) {
#pragma unroll
            for (int reg = 0; reg < 4; reg++) {
                const int t = t0 + wm + mi * 16 + quad * 4 + reg;
                outb[(size_t)t * DMODEL + o] = acc[mi][ni][reg] + bvv;
            }
        }
    }
}

extern "C" void kernel_launch(void* const* d_in, const int* in_sizes, int n_in,
                              void* d_out, int out_size, void* d_ws, size_t ws_size,
                              hipStream_t stream) {
    const float* x    = (const float*)d_in[0];   // (32, 2048, 7) fp32
    const float* W    = (const float*)d_in[1];   // (512, 56, 3) fp32
    const float* bias = (const float*)d_in[2];   // (512,) fp32
    float* out        = (float*)d_out;           // (32, 2048, 512) fp32

    const size_t g_bytes = (size_t)NROWS * RB;          // 9,437,184
    const size_t w_bytes = (size_t)3 * DMODEL * RB;     //   221,184
    if (ws_size >= g_bytes + w_bytes) {
        __hip_bfloat16* G   = (__hip_bfloat16*)d_ws;
        __hip_bfloat16* Wb2 = (__hip_bfloat16*)((char*)d_ws + g_bytes);
        hipLaunchKernelGGL(prep_kernel, dim3(262), dim3(256), 0, stream, x, W, G, Wb2);
        hipLaunchKernelGGL(gemm_kernel, dim3((NROWS / BM) * (DMODEL / BN)), dim3(256), 0, stream,
                           G, Wb2, bias, out);
    } else {
        hipLaunchKernelGGL(fused_tokenconv_kernel, dim3(32 * 16 * 4), dim3(256), 0, stream,
                           x, W, bias, out);
    }
}

// Round 5
// 158.416 us; speedup vs baseline: 1.0252x; 1.0252x over previous
//
#include <hip/hip_runtime.h>
#include <hip/hip_bf16.h>
#include <stdint.h>

// out[b,t,o] = bias[o] + sum_{c<7,m<8,h<3} W[o, c*8+m, h] * Z[b, c*8+m, (t+h-1)&2047]
// Z[b, cm, s] = (s >= 168) ? x[b, s-24m, c] : 0
//
// Tap decomposition: out = sum_h Wh[h] @ G_shift(h-1)^T with
//   G[b*2048+t][c*8+m] = (t>=168) ? x[b, t-24m, c] : 0  (K=56, pad 72 in G rows)
// MFMA orientation: A-operand = W (m=o), B-operand = G (n=t) so that C/D regs
// hold 4 consecutive o -> dwordx4 stores. W is pre-swizzled to exact A-fragment
// lane order: one coalesced 1 KB global load per wave fragment, no LDS for W.

#define TAO    24
#define MTAPS  7
#define C_IN   7
#define SEQ    2048
#define DMODEL 512
#define KP     72      // G row padded K (bf16), 144 B
#define RB     144     // G row bytes (odd multiple of 16B -> free 2-way LDS alias)
#define NROWS  65536   // 32*2048
#define BO     128     // o per block
#define BT     128     // t per block
#define AROWS  130     // BT + 2 halo rows
#define A_CHUNKS (AROWS * 9)   // 1170 x 16B

typedef __attribute__((ext_vector_type(8))) short frag_ab;  // 8 bf16
typedef __attribute__((ext_vector_type(4))) float frag_cd;  // 4 fp32

// ---------------- phase 1: build G + fragment-swizzled W ----------------
// blocks [0,256): G rows.
// blocks [256,304): Wfrag[((h*32+oc)*2+kc)*64 + lane] (16 B each):
//   Wfrag[...][j] = W[o*168 + k*3 + h], o = oc*16 + (lane&15),
//                   k = kc*32 + (lane>>4)*8 + j, zero for k >= 56.
__global__ __launch_bounds__(256)
void prep_kernel(const float* __restrict__ x, const float* __restrict__ W,
                 __hip_bfloat16* __restrict__ G, __hip_bfloat16* __restrict__ Wf)
{
    const int tid = threadIdx.x;
    if (blockIdx.x < 256) {
        const int row = blockIdx.x * 256 + tid;
        const int b   = row >> 11;
        const int t   = row & (SEQ - 1);
        const float* xb = x + b * (SEQ * C_IN);

        union { __hip_bfloat16 h[KP]; int4 v[9]; } u;
#pragma unroll
        for (int j = 0; j < 9; j++) u.v[j] = (int4){0, 0, 0, 0};

        if (t >= MTAPS * TAO) {
#pragma unroll
            for (int m = 0; m < 8; m++) {
                const float* p = xb + (t - TAO * m) * C_IN;
#pragma unroll
                for (int c = 0; c < C_IN; c++)
                    u.h[c * 8 + m] = __float2bfloat16(p[c]);
            }
        }
        int4* dst = (int4*)((char*)G + (size_t)row * RB);
#pragma unroll
        for (int j = 0; j < 9; j++) dst[j] = u.v[j];
    } else {
        const int idx  = (blockIdx.x - 256) * 256 + tid;   // [0, 12288)
        const int lane = idx & 63;
        const int kc   = (idx >> 6) & 1;
        const int oc   = (idx >> 7) & 31;
        const int h    = idx >> 12;
        const int o    = oc * 16 + (lane & 15);
        const int kof  = kc * 32 + (lane >> 4) * 8;

        union { __hip_bfloat16 s[8]; int4 v; } u;
#pragma unroll
        for (int j = 0; j < 8; j++) {
            const int k = kof + j;
            float v = (k < 56) ? W[o * 168 + k * 3 + h] : 0.0f;
            u.s[j] = __float2bfloat16(v);
        }
        ((int4*)Wf)[idx] = u.v;
    }
}

// ---------------- phase 2: GEMM ----------------
__global__ __launch_bounds__(256, 3)
void gemm_kernel(const __hip_bfloat16* __restrict__ G,
                 const __hip_bfloat16* __restrict__ Wf,
                 const float* __restrict__ bias,
                 float* __restrict__ out)
{
    __shared__ __align__(16) char As[AROWS * RB];   // 18720 B: G tile only

    const int tid = threadIdx.x;
    const int bo  = blockIdx.x & 3;      // 4 o-blocks
    const int mb  = blockIdx.x >> 2;     // 512 t-blocks
    const int b   = mb >> 4;
    const int t0  = (mb & 15) * BT;
    const int o0  = bo * BO;

    // --- stage G tile: rows t0-1 .. t0+128 (circular, matches reference pad)
    {
        const char* Gb = (const char*)G + (size_t)b * SEQ * RB;
        for (int q = tid; q < A_CHUNKS; q += 256) {
            const int row = q / 9;
            const int c16 = q - row * 9;
            const int srow = (t0 - 1 + row + SEQ) & (SEQ - 1);
            __builtin_amdgcn_global_load_lds(
                (const __attribute__((address_space(1))) uint32_t*)(Gb + (size_t)srow * RB + c16 * 16),
                (__attribute__((address_space(3))) uint32_t*)(As + q * 16), 16, 0, 0);
        }
    }

    // --- wave geometry; waves 2(o) x 2(t); wave tile 64 o x 64 t
    const int wave = tid >> 6;
    const int lane = tid & 63;
    const int wo   = (wave >> 1) * 64;
    const int wt   = (wave & 1) * 64;
    const int l15  = lane & 15;
    const int quad = lane >> 4;

    // bias preload: 4 consecutive floats per mi (o = o0+wo+mi*16+quad*4)
    float4 bias4[4];
#pragma unroll
    for (int mi = 0; mi < 4; mi++)
        bias4[mi] = *(const float4*)&bias[o0 + wo + mi * 16 + quad * 4];

    frag_cd acc[4][4];
#pragma unroll
    for (int i = 0; i < 4; i++)
#pragma unroll
        for (int j = 0; j < 4; j++)
            acc[i][j] = (frag_cd){0.f, 0.f, 0.f, 0.f};

    __syncthreads();

    // --- K loop: 3 taps x 2 k-chunks; W frags direct from global (L1/L2 hot)
    const int octile = bo * 8 + (wo >> 4);   // o-chunk base (units of 16 o)
#pragma unroll
    for (int h = 0; h < 3; h++) {
#pragma unroll
        for (int kc = 0; kc < 2; kc++) {
            frag_ab wfr[4], gfr[4];
#pragma unroll
            for (int mi = 0; mi < 4; mi++) {
                const int tile = (h * 32 + octile + mi) * 2 + kc;
                wfr[mi] = *(const frag_ab*)((const char*)Wf + (size_t)tile * 1024 + lane * 16);
            }
            const int kbyte = kc * 64 + quad * 16;
#pragma unroll
            for (int ni = 0; ni < 4; ni++)
                gfr[ni] = *(const frag_ab*)(As + (wt + ni * 16 + l15 + h) * RB + kbyte);
#pragma unroll
            for (int mi = 0; mi < 4; mi++)
#pragma unroll
                for (int ni = 0; ni < 4; ni++)
                    acc[mi][ni] = __builtin_amdgcn_mfma_f32_16x16x32_bf16(
                        wfr[mi], gfr[ni], acc[mi][ni], 0, 0, 0);
        }
    }

    // --- epilogue: C/D col = lane&15 = t, row = quad*4+reg = o -> dwordx4
    const size_t rowbase = (size_t)b * SEQ + t0 + wt;
#pragma unroll
    for (int ni = 0; ni < 4; ni++) {
        const size_t r = rowbase + ni * 16 + l15;
        float* orow = out + r * DMODEL + o0 + wo + quad * 4;
#pragma unroll
        for (int mi = 0; mi < 4; mi++) {
            float4 v;
            v.x = acc[mi][ni][0] + bias4[mi].x;
            v.y = acc[mi][ni][1] + bias4[mi].y;
            v.z = acc[mi][ni][2] + bias4[mi].z;
            v.w = acc[mi][ni][3] + bias4[mi].w;
            *(float4*)(orow + mi * 16) = v;
        }
    }
}

// ---------------- fallback (round-1, known-correct, no ws) ----------------
#define KDIM  168
#define KPAD  192
#define FLDK  200
__global__ __launch_bounds__(256, 1)
void fused_tokenconv_kernel(const float* __restrict__ x,
                            const float* __restrict__ W,
                            const float* __restrict__ bias,
                            float* __restrict__ out)
{
    __shared__ __hip_bfloat16 As[128][FLDK];
    __shared__ __hip_bfloat16 Bs[128][FLDK];
    const int tid = threadIdx.x;
    const int blk = blockIdx.x;
    const int nb  = blk & 3;
    const int mb  = blk >> 2;
    const int b   = mb >> 4;
    const int t0  = (mb & 15) * 128;
    const int o0  = nb * 128;
    const float* xb = x + b * (SEQ * C_IN);

    for (int idx = tid; idx < 128 * KPAD; idx += 256) {
        int o_l = idx / KPAD;
        int i   = idx - o_l * KPAD;
        float v = (i < KDIM) ? W[(o0 + o_l) * KDIM + i] : 0.0f;
        Bs[o_l][i] = __float2bfloat16(v);
    }
    for (int idx = tid; idx < 128 * KPAD; idx += 256) {
        int t_l = idx / KPAD;
        int i   = idx - t_l * KPAD;
        float v = 0.0f;
        if (i < KDIM) {
            int c = i / 24;
            int r = i - c * 24;
            int m = r / 3;
            int h = r - m * 3;
            int s = (t0 + t_l + h - 1 + SEQ) & (SEQ - 1);
            if (s >= MTAPS * TAO) v = xb[(s - TAO * m) * C_IN + c];
        }
        As[t_l][i] = __float2bfloat16(v);
    }
    __syncthreads();

    const int wave = tid >> 6;
    const int lane = tid & 63;
    const int wm   = (wave >> 1) * 64;
    const int wn   = (wave & 1) * 64;
    const int l15  = lane & 15;
    const int quad = lane >> 4;

    frag_cd acc[4][4];
#pragma unroll
    for (int i = 0; i < 4; i++)
#pragma unroll
        for (int j = 0; j < 4; j++)
            acc[i][j] = (frag_cd){0.f, 0.f, 0.f, 0.f};

#pragma unroll
    for (int kc = 0; kc < KPAD / 32; kc++) {
        const int kof = kc * 32 + quad * 8;
        frag_ab a[4], bf[4];
#pragma unroll
        for (int mi = 0; mi < 4; mi++)
            a[mi] = *(const frag_ab*)&As[wm + mi * 16 + l15][kof];
#pragma unroll
        for (int ni = 0; ni < 4; ni++)
            bf[ni] = *(const frag_ab*)&Bs[wn + ni * 16 + l15][kof];
#pragma unroll
        for (int mi = 0; mi < 4; mi++)
#pragma unroll
            for (int ni = 0; ni < 4; ni++)
                acc[mi][ni] = __builtin_amdgcn_mfma_f32_16x16x32_bf16(
                    a[mi], bf[ni], acc[mi][ni], 0, 0, 0);
    }
    float* outb = out + (size_t)b * SEQ * DMODEL;
#pragma unroll
    for (int ni = 0; ni < 4; ni++) {
        const int o  = o0 + wn + ni * 16 + l15;
        const float bvv = bias[o];
#pragma unroll
        for (int mi = 0; mi < 4; mi++) {
#pragma unroll
            for (int reg = 0; reg < 4; reg++) {
                const int t = t0 + wm + mi * 16 + quad * 4 + reg;
                outb[(size_t)t * DMODEL + o] = acc[mi][ni][reg] + bvv;
            }
        }
    }
}

extern "C" void kernel_launch(void* const* d_in, const int* in_sizes, int n_in,
                              void* d_out, int out_size, void* d_ws, size_t ws_size,
                              hipStream_t stream) {
    const float* x    = (const float*)d_in[0];   // (32, 2048, 7) fp32
    const float* W    = (const float*)d_in[1];   // (512, 56, 3) fp32
    const float* bias = (const float*)d_in[2];   // (512,) fp32
    float* out        = (float*)d_out;           // (32, 2048, 512) fp32

    const size_t g_bytes = (size_t)NROWS * RB;          // 9,437,184
    const size_t w_bytes = (size_t)12288 * 16;          //   196,608
    if (ws_size >= g_bytes + w_bytes) {
        __hip_bfloat16* G  = (__hip_bfloat16*)d_ws;
        __hip_bfloat16* Wf = (__hip_bfloat16*)((char*)d_ws + g_bytes);
        hipLaunchKernelGGL(prep_kernel, dim3(304), dim3(256), 0, stream, x, W, G, Wf);
        hipLaunchKernelGGL(gemm_kernel, dim3((DMODEL / BO) * (NROWS / BT)), dim3(256), 0, stream,
                           G, Wf, bias, out);
    } else {
        hipLaunchKernelGGL(fused_tokenconv_kernel, dim3(32 * 16 * 4), dim3(256), 0, stream,
                           x, W, bias, out);
    }
}

// Round 6
// 153.512 us; speedup vs baseline: 1.0579x; 1.0319x over previous
//
#include <hip/hip_runtime.h>
#include <hip/hip_bf16.h>
#include <stdint.h>

// out[b,t,o] = bias[o] + sum_{c<7,m<8,h<3} W[o, c*8+m, h] * Z[b, c*8+m, (t+h-1)&2047]
// Z[b, cm, s] = (s >= 168) ? x[b, s-24m, c] : 0
//
// Fused design: no materialized G. For MFMA fragment chunk qp = kc*4+quad the
// 8 k-components are k = 8*qp + j  ->  c = qp, m = j, so a G B-fragment is
// x[tt-24j][qp]: 8 LDS u16 reads at immediate offsets from one base.
// lrow = local+169-24j in [0,297] with NO modulo (wraps cancel).
// A-operand = W (pre-swizzled Wf, direct global loads), B-operand = G.
// C/D regs hold 4 consecutive o -> dwordx4 stores.

#define TAO    24
#define MTAPS  7
#define C_IN   7
#define SEQ    2048
#define DMODEL 512
#define NROWS  65536   // 32*2048
#define BO     128     // o per block
#define BT     128     // t per block
#define XROWS  298     // staged x rows: t0-169 .. t0+128
#define XPLANE 304     // padded plane stride (elements)

typedef __attribute__((ext_vector_type(8))) short frag_ab;  // 8 bf16
typedef __attribute__((ext_vector_type(4))) float frag_cd;  // 4 fp32

// ---------------- prep: fragment-swizzled W only ----------------
// Wf[((h*32+oc)*2+kc)*64 + lane][j] = W[o*168 + k*3 + h],
//   o = oc*16 + (lane&15), k = kc*32 + (lane>>4)*8 + j, zero for k >= 56.
__global__ __launch_bounds__(256)
void prep_w_kernel(const float* __restrict__ W, __hip_bfloat16* __restrict__ Wf)
{
    const int idx  = blockIdx.x * 256 + threadIdx.x;   // [0, 12288)
    const int lane = idx & 63;
    const int kc   = (idx >> 6) & 1;
    const int oc   = (idx >> 7) & 31;
    const int h    = idx >> 12;
    const int o    = oc * 16 + (lane & 15);
    const int kof  = kc * 32 + (lane >> 4) * 8;

    union { __hip_bfloat16 s[8]; int4 v; } u;
#pragma unroll
    for (int j = 0; j < 8; j++) {
        const int k = kof + j;
        float v = (k < 56) ? W[o * 168 + k * 3 + h] : 0.0f;
        u.s[j] = __float2bfloat16(v);
    }
    ((int4*)Wf)[idx] = u.v;
}

// ---------------- fused GEMM ----------------
__global__ __launch_bounds__(256, 3)
void gemm_kernel(const float* __restrict__ x,
                 const __hip_bfloat16* __restrict__ Wf,
                 const float* __restrict__ bias,
                 float* __restrict__ out)
{
    __shared__ short xt[8 * XPLANE];   // 4864 B; plane c: bf16 x[.,c] by local row

    const int tid = threadIdx.x;
    const int bo  = blockIdx.x & 3;      // 4 o-blocks
    const int mb  = blockIdx.x >> 2;     // 512 t-blocks
    const int b   = mb >> 4;
    const int t0  = (mb & 15) * BT;
    const int o0  = bo * BO;

    // --- stage x window: rows (t0-169+r)&2047, r in [0,298), channels 0..6
    {
        const float* xb = x + b * (SEQ * C_IN);
        const int base = (t0 - 169 + SEQ) & (SEQ - 1);
#pragma unroll
        for (int it = 0; it < 9; it++) {
            const int idx = it * 256 + tid;           // r*7 + c
            if (idx < XROWS * C_IN) {
                const int r = idx / 7;
                const int c = idx - r * 7;
                const int xrow = (base + r) & (SEQ - 1);
                const float v = xb[xrow * C_IN + c];
                __hip_bfloat16 bv = __float2bfloat16(v);
                xt[c * XPLANE + r] = *reinterpret_cast<short*>(&bv);
            }
        }
    }

    // --- wave geometry; waves 2(o) x 2(t); wave tile 64 o x 64 t
    const int wave = tid >> 6;
    const int lane = tid & 63;
    const int wo   = (wave >> 1) * 64;
    const int wt   = (wave & 1) * 64;
    const int l15  = lane & 15;
    const int quad = lane >> 4;

    float4 bias4[4];
#pragma unroll
    for (int mi = 0; mi < 4; mi++)
        bias4[mi] = *(const float4*)&bias[o0 + wo + mi * 16 + quad * 4];

    frag_cd acc[4][4];
#pragma unroll
    for (int i = 0; i < 4; i++)
#pragma unroll
        for (int j = 0; j < 4; j++)
            acc[i][j] = (frag_cd){0.f, 0.f, 0.f, 0.f};

    __syncthreads();

    const int octile = bo * 8 + (wo >> 4);   // o-chunk base (units of 16 o)
#pragma unroll
    for (int h = 0; h < 3; h++) {
#pragma unroll
        for (int kc = 0; kc < 2; kc++) {
            const int qp = kc * 4 + quad;            // channel plane
            frag_ab wfr[4];
#pragma unroll
            for (int mi = 0; mi < 4; mi++) {
                const int tile = (h * 32 + octile + mi) * 2 + kc;
                wfr[mi] = *(const frag_ab*)((const char*)Wf + (size_t)tile * 1024 + lane * 16);
            }
            // --- build G fragments in-register from xt
            union { short s[8]; frag_ab f; int4 i4; } g[4];
#pragma unroll
            for (int ni = 0; ni < 4; ni++) {
                const int lbase = wt + ni * 16 + l15 + h;          // local+1 >= 0
                const int ttw = (t0 + lbase - 1 + SEQ) & (SEQ - 1);
                const short* p = &xt[qp * XPLANE + lbase];
#pragma unroll
                for (int j = 0; j < 8; j++)
                    g[ni].s[j] = p[168 - 24 * j];                  // imm offsets 0..336B
                const bool valid = (ttw >= MTAPS * TAO) && (qp < 7);
                g[ni].i4.x = valid ? g[ni].i4.x : 0;
                g[ni].i4.y = valid ? g[ni].i4.y : 0;
                g[ni].i4.z = valid ? g[ni].i4.z : 0;
                g[ni].i4.w = valid ? g[ni].i4.w : 0;
            }
#pragma unroll
            for (int mi = 0; mi < 4; mi++)
#pragma unroll
                for (int ni = 0; ni < 4; ni++)
                    acc[mi][ni] = __builtin_amdgcn_mfma_f32_16x16x32_bf16(
                        wfr[mi], g[ni].f, acc[mi][ni], 0, 0, 0);
        }
    }

    // --- epilogue: C/D col = lane&15 = t, row = quad*4+reg = o -> dwordx4
    const size_t rowbase = (size_t)b * SEQ + t0 + wt;
#pragma unroll
    for (int ni = 0; ni < 4; ni++) {
        const size_t r = rowbase + ni * 16 + l15;
        float* orow = out + r * DMODEL + o0 + wo + quad * 4;
#pragma unroll
        for (int mi = 0; mi < 4; mi++) {
            float4 v;
            v.x = acc[mi][ni][0] + bias4[mi].x;
            v.y = acc[mi][ni][1] + bias4[mi].y;
            v.z = acc[mi][ni][2] + bias4[mi].z;
            v.w = acc[mi][ni][3] + bias4[mi].w;
            *(float4*)(orow + mi * 16) = v;
        }
    }
}

// ---------------- fallback (round-1, known-correct, no ws) ----------------
#define KDIM  168
#define KPAD  192
#define FLDK  200
__global__ __launch_bounds__(256, 1)
void fused_tokenconv_kernel(const float* __restrict__ x,
                            const float* __restrict__ W,
                            const float* __restrict__ bias,
                            float* __restrict__ out)
{
    __shared__ __hip_bfloat16 As[128][FLDK];
    __shared__ __hip_bfloat16 Bs[128][FLDK];
    const int tid = threadIdx.x;
    const int blk = blockIdx.x;
    const int nb  = blk & 3;
    const int mb  = blk >> 2;
    const int b   = mb >> 4;
    const int t0  = (mb & 15) * 128;
    const int o0  = nb * 128;
    const float* xb = x + b * (SEQ * C_IN);

    for (int idx = tid; idx < 128 * KPAD; idx += 256) {
        int o_l = idx / KPAD;
        int i   = idx - o_l * KPAD;
        float v = (i < KDIM) ? W[(o0 + o_l) * KDIM + i] : 0.0f;
        Bs[o_l][i] = __float2bfloat16(v);
    }
    for (int idx = tid; idx < 128 * KPAD; idx += 256) {
        int t_l = idx / KPAD;
        int i   = idx - t_l * KPAD;
        float v = 0.0f;
        if (i < KDIM) {
            int c = i / 24;
            int r = i - c * 24;
            int m = r / 3;
            int h = r - m * 3;
            int s = (t0 + t_l + h - 1 + SEQ) & (SEQ - 1);
            if (s >= MTAPS * TAO) v = xb[(s - TAO * m) * C_IN + c];
        }
        As[t_l][i] = __float2bfloat16(v);
    }
    __syncthreads();

    const int wave = tid >> 6;
    const int lane = tid & 63;
    const int wm   = (wave >> 1) * 64;
    const int wn   = (wave & 1) * 64;
    const int l15  = lane & 15;
    const int quad = lane >> 4;

    frag_cd acc[4][4];
#pragma unroll
    for (int i = 0; i < 4; i++)
#pragma unroll
        for (int j = 0; j < 4; j++)
            acc[i][j] = (frag_cd){0.f, 0.f, 0.f, 0.f};

#pragma unroll
    for (int kc = 0; kc < KPAD / 32; kc++) {
        const int kof = kc * 32 + quad * 8;
        frag_ab a[4], bf[4];
#pragma unroll
        for (int mi = 0; mi < 4; mi++)
            a[mi] = *(const frag_ab*)&As[wm + mi * 16 + l15][kof];
#pragma unroll
        for (int ni = 0; ni < 4; ni++)
            bf[ni] = *(const frag_ab*)&Bs[wn + ni * 16 + l15][kof];
#pragma unroll
        for (int mi = 0; mi < 4; mi++)
#pragma unroll
            for (int ni = 0; ni < 4; ni++)
                acc[mi][ni] = __builtin_amdgcn_mfma_f32_16x16x32_bf16(
                    a[mi], bf[ni], acc[mi][ni], 0, 0, 0);
    }
    float* outb = out + (size_t)b * SEQ * DMODEL;
#pragma unroll
    for (int ni = 0; ni < 4; ni++) {
        const int o  = o0 + wn + ni * 16 + l15;
        const float bvv = bias[o];
#pragma unroll
        for (int mi = 0; mi < 4; mi++) {
#pragma unroll
            for (int reg = 0; reg < 4; reg++) {
                const int t = t0 + wm + mi * 16 + quad * 4 + reg;
                outb[(size_t)t * DMODEL + o] = acc[mi][ni][reg] + bvv;
            }
        }
    }
}

extern "C" void kernel_launch(void* const* d_in, const int* in_sizes, int n_in,
                              void* d_out, int out_size, void* d_ws, size_t ws_size,
                              hipStream_t stream) {
    const float* x    = (const float*)d_in[0];   // (32, 2048, 7) fp32
    const float* W    = (const float*)d_in[1];   // (512, 56, 3) fp32
    const float* bias = (const float*)d_in[2];   // (512,) fp32
    float* out        = (float*)d_out;           // (32, 2048, 512) fp32

    const size_t w_bytes = (size_t)12288 * 16;   // 196,608
    if (ws_size >= w_bytes) {
        __hip_bfloat16* Wf = (__hip_bfloat16*)d_ws;
        hipLaunchKernelGGL(prep_w_kernel, dim3(48), dim3(256), 0, stream, W, Wf);
        hipLaunchKernelGGL(gemm_kernel, dim3((DMODEL / BO) * (NROWS / BT)), dim3(256), 0, stream,
                           x, Wf, bias, out);
    } else {
        hipLaunchKernelGGL(fused_tokenconv_kernel, dim3(32 * 16 * 4), dim3(256), 0, stream,
                           x, W, bias, out);
    }
}